// Round 7
// baseline (263.811 us; speedup 1.0000x reference)
//
#include <hip/hip_runtime.h>
#include <hip/hip_cooperative_groups.h>

namespace cg = cooperative_groups;

#define PRESCALE 2.8853900817779268f   // 2*log2(e): exp2(PRESCALE*x) = e^{2x}

typedef short s16;
typedef unsigned short u16;
typedef unsigned int u32;
typedef __attribute__((ext_vector_type(8))) short short8v;  // 8 bf16 (4 VGPRs)
typedef __attribute__((ext_vector_type(4))) float f4;

// Raw v_exp_f32 / v_rcp_f32 — OCML exp2f carries denorm fixups (~3x VALU).
#if defined(__has_builtin)
#if __has_builtin(__builtin_amdgcn_exp2f)
#define EXP2(x) __builtin_amdgcn_exp2f(x)
#endif
#endif
#ifndef EXP2
#define EXP2(x) exp2f(x)
#endif
#define RCP(x) __builtin_amdgcn_rcpf(x)

__device__ inline u16 f2bf(float f){
  union{u32 i; float f;} v; v.f = f;
  u32 r = v.i + 0x7fffu + ((v.i >> 16) & 1u);
  return (u16)(r >> 16);
}

struct Ptrs {
  const int* question; const float* img_feat; const float* emb;
  const float* W_img; const float* b_img; const float* W_ai;
  const float* W_aw; const float* b_aw; const float* w_att;
  float* out;
  s16* Wb; s16* Xb; s16* Eb; float* img; s16* img_b;
  float* AWT4; float* ST;
};

#define SMEM_BYTES 34816   // max phase need: score 16*512*4 + 512*4

// ---------------- P0: conversions + emb gather. grid-stride, 360448 float4 units.
__device__ void phase_prep(const Ptrs& P, int bx, int tid, int nblk){
  for (int g = bx*256 + tid; g < 360448; g += nblk*256){
    if (g < 196608){                    // 3 weights -> bf16 (PRESCALE on W_ai, W_aw)
      const int i = g*4, w = i >> 18;
      const float sc = (w == 0) ? 1.f : PRESCALE;
      const float* src = (w==0) ? P.W_img : ((w==1) ? P.W_ai : P.W_aw);
      float4 v = *reinterpret_cast<const float4*>(src + (i & 262143));
      ushort4 o; o.x=f2bf(v.x*sc); o.y=f2bf(v.y*sc); o.z=f2bf(v.z*sc); o.w=f2bf(v.w*sc);
      *reinterpret_cast<ushort4*>(P.Wb + i) = o;
    } else if (g < 229376){             // Xb 256x512 bf16, zero-pad rows >=196
      const int i = (g - 196608)*4;
      ushort4 o = make_ushort4(0,0,0,0);
      if ((i >> 9) < 196){
        float4 v = *reinterpret_cast<const float4*>(P.img_feat + i);
        o.x=f2bf(v.x); o.y=f2bf(v.y); o.z=f2bf(v.z); o.w=f2bf(v.w);
      }
      *reinterpret_cast<ushort4*>(P.Xb + i) = o;
    } else {                            // Eb 1024x512 bf16 + f32 copy to out[:,512:]
      const int i = (g - 229376)*4;
      const int t = i >> 9, c = i & 511;
      float4 v = *reinterpret_cast<const float4*>(P.emb + (size_t)P.question[t]*512 + c);
      *reinterpret_cast<float4*>(P.out + (size_t)t*1024 + 512 + c) = v;
      ushort4 o; o.x=f2bf(v.x); o.y=f2bf(v.y); o.z=f2bf(v.z); o.w=f2bf(v.w);
      *reinterpret_cast<ushort4*>(P.Eb + i) = o;
    }
  }
}

// 64x64 MFMA tile core: D[i][j] = sum_k A[i][k]*B[j][k], K=512 bf16.
__device__ inline void mfma_core(const s16* __restrict__ A, const s16* __restrict__ B,
                                 int m0, int n0, int lr, int lg, f4 acc[2][2]){
  const s16* pa0 = A + (size_t)(m0 + lr)*512 + lg*8;
  const s16* pa1 = pa0 + 16*512;
  const s16* pb0 = B + (size_t)(n0 + lr)*512 + lg*8;
  const s16* pb1 = pb0 + 16*512;
  #pragma unroll 4
  for (int k = 0; k < 512; k += 32){
    short8v a0 = *reinterpret_cast<const short8v*>(pa0 + k);
    short8v a1 = *reinterpret_cast<const short8v*>(pa1 + k);
    short8v b0 = *reinterpret_cast<const short8v*>(pb0 + k);
    short8v b1 = *reinterpret_cast<const short8v*>(pb1 + k);
    acc[0][0] = __builtin_amdgcn_mfma_f32_16x16x32_bf16(a0, b0, acc[0][0], 0, 0, 0);
    acc[0][1] = __builtin_amdgcn_mfma_f32_16x16x32_bf16(a0, b1, acc[0][1], 0, 0, 0);
    acc[1][0] = __builtin_amdgcn_mfma_f32_16x16x32_bf16(a1, b0, acc[1][0], 0, 0, 0);
    acc[1][1] = __builtin_amdgcn_mfma_f32_16x16x32_bf16(a1, b1, acc[1][1], 0, 0, 0);
  }
}

// ---------------- P1: img GEMM (blocks 0..31) + AWT GEMM (blocks 32..159).
__device__ void phase_gemms(const Ptrs& P, int bx, int tid){
  if (bx >= 160) return;
  const int w = tid>>6, l = tid&63, lr = l&15, lg = l>>4;
  f4 acc[2][2] = {};
  if (bx < 32){
    const int m0 = (bx >> 3)*64 + (w>>1)*32;
    const int n0 = (bx & 7)*64 + (w&1)*32;
    mfma_core(P.Xb, P.Wb, m0, n0, lr, lg, acc);
    #pragma unroll
    for (int i = 0; i < 2; ++i){
      #pragma unroll
      for (int j = 0; j < 2; ++j){
        const int nn = n0 + j*16 + lr;
        const float bc = P.b_img[nn];
        #pragma unroll
        for (int p = 0; p < 4; ++p){
          const int mm = m0 + i*16 + lg*4 + p;
          float v = fmaxf(acc[i][j][p] + bc, 0.f);
          P.img[(size_t)mm*512 + nn] = v;
          P.img_b[(size_t)mm*512 + nn] = (s16)f2bf(v);
        }
      }
    }
  } else {
    const int blk = bx - 32;
    const int m0 = (blk >> 4)*64 + (w>>1)*32;     // h
    const int n0 = (blk & 15)*64 + (w&1)*32;      // t
    mfma_core(P.Wb + 524288, P.Eb, m0, n0, lr, lg, acc);
    #pragma unroll
    for (int i = 0; i < 2; ++i){
      const int mb = m0 + i*16 + lg*4;            // h = mb+p, mb%4==0
      #pragma unroll
      for (int j = 0; j < 2; ++j){
        const int nn = n0 + j*16 + lr;
        f4 o;
        #pragma unroll
        for (int p = 0; p < 4; ++p)
          o[p] = acc[i][j][p] + P.b_aw[mb+p]*PRESCALE;
        *reinterpret_cast<f4*>(P.AWT4 + (size_t)(mb>>2)*4096 + nn*4) = o;
      }
    }
  }
}

// ---------------- P2: score with fused AI-GEMM. blocks 0..399.
// AI16 = img_b[16 rows] @ Wb_ai^T -> LDS; then
// ST[r][t] = sum_h w[h]*rcp(exp2(AI'[r][h]+AW'[h][t])+1); softmax == softmax(-2*ST)
__device__ void phase_score(const Ptrs& P, char* smemc, int bx, int tid){
  if (bx >= 400) return;
  float* ais = (float*)smemc;          // [16][512]
  float* wsh = (float*)smemc + 8192;   // [512]
  const int w = tid>>6, l = tid&63, lr = l&15, lg = l>>4;
  const int rq = bx>>4, tq = bx&15;
  const int arow0 = (rq>>1)*16;        // 16-row AI tile shared by rq pairs
  {
    const s16* pa = P.img_b + (size_t)(arow0+lr)*512 + lg*8;
    const s16* pb = P.Wb + 262144 + (size_t)(w*128+lr)*512 + lg*8;
    f4 acc[8] = {};
    #pragma unroll 2
    for (int ks = 0; ks < 16; ++ks){
      short8v a = *reinterpret_cast<const short8v*>(pa + ks*32);
      #pragma unroll
      for (int nf = 0; nf < 8; ++nf){
        short8v b = *reinterpret_cast<const short8v*>(pb + ks*32 + nf*8192);
        acc[nf] = __builtin_amdgcn_mfma_f32_16x16x32_bf16(a, b, acc[nf], 0, 0, 0);
      }
    }
    #pragma unroll
    for (int nf = 0; nf < 8; ++nf)
      #pragma unroll
      for (int p = 0; p < 4; ++p)
        ais[(size_t)(lg*4+p)*512 + w*128 + nf*16 + lr] = acc[nf][p];
  }
  if (tid < 128)
    reinterpret_cast<float4*>(wsh)[tid] = reinterpret_cast<const float4*>(P.w_att)[tid];
  __syncthreads();

  const int roff = (rq&1)*8;
  const float* a0 = ais + (size_t)(roff + w*2)*512;
  const float* a1 = a0 + 512;
  const int t = tq*64 + l;
  const float* ap = P.AWT4 + (size_t)t*4;
  float s0=0.f, s1=0.f, s2=0.f, s3=0.f;
  #pragma unroll 4
  for (int hg = 0; hg < 128; ++hg){
    f4 x  = *reinterpret_cast<const f4*>(ap + (size_t)hg*4096);
    f4 av = *reinterpret_cast<const f4*>(a0 + hg*4);
    f4 bv = *reinterpret_cast<const f4*>(a1 + hg*4);
    f4 wv = *reinterpret_cast<const f4*>(wsh + hg*4);
    s0 += wv.x*RCP(EXP2(av.x+x.x)+1.f) + wv.y*RCP(EXP2(av.y+x.y)+1.f);
    s1 += wv.z*RCP(EXP2(av.z+x.z)+1.f) + wv.w*RCP(EXP2(av.w+x.w)+1.f);
    s2 += wv.x*RCP(EXP2(bv.x+x.x)+1.f) + wv.y*RCP(EXP2(bv.y+x.y)+1.f);
    s3 += wv.z*RCP(EXP2(bv.z+x.z)+1.f) + wv.w*RCP(EXP2(bv.w+x.w)+1.f);
  }
  const int r = rq*8 + w*2;
  if (r < 196)     P.ST[(size_t)r*1024 + t]     = s0+s1;
  if (r+1 < 196)   P.ST[(size_t)(r+1)*1024 + t] = s2+s3;
}

// ---------------- P3: softmax(-2*ST) (fold /196) + ctx = w @ img. 512 blocks.
__device__ void phase_ctx(const Ptrs& P, char* smemc, int bx, int tid){
  float (*wgt)[16] = (float(*)[16])smemc;                // [196][16]
  float (*red)[16] = (float(*)[16])(smemc + 12544);      // [16][16]
  const int t0 = (bx>>3)*16, e0 = (bx&7)*64;
  const int rs = tid>>4, tl = tid&15;

  float m = 1e30f;
  for (int k = 0; k < 13; ++k){
    const int r = rs + 16*k;
    if (r < 196) m = fminf(m, P.ST[(size_t)r*1024 + t0 + tl]);
  }
  red[rs][tl] = m;
  __syncthreads();
  if (tid < 16){
    float mm = red[0][tid];
    #pragma unroll
    for (int i = 1; i < 16; ++i) mm = fminf(mm, red[i][tid]);
    red[0][tid] = mm;
  }
  __syncthreads();
  const float mt = red[0][tl];
  float sum = 0.f;
  for (int k = 0; k < 13; ++k){
    const int r = rs + 16*k;
    if (r < 196){
      float p = EXP2(PRESCALE*(mt - P.ST[(size_t)r*1024 + t0 + tl]));
      wgt[r][tl] = p;
      sum += p;
    }
  }
  __syncthreads();
  red[rs][tl] = sum;
  __syncthreads();
  if (tid < 16){
    float ss = 0.f;
    #pragma unroll
    for (int i = 0; i < 16; ++i) ss += red[i][tid];
    red[0][tid] = 1.f / (ss * 196.f);
  }
  __syncthreads();
  const float inv = red[0][tl];
  for (int k = 0; k < 13; ++k){
    const int r = rs + 16*k;
    if (r < 196) wgt[r][tl] *= inv;
  }
  __syncthreads();

  const int e = e0 + (tid & 63), tq = tid >> 6;
  float acc[4] = {0.f, 0.f, 0.f, 0.f};
  const float* ip = P.img + e;
  #pragma unroll 4
  for (int r = 0; r < 196; ++r){
    const float f = ip[(size_t)r*512];
    float4 w4 = *reinterpret_cast<const float4*>(&wgt[r][tq*4]);
    acc[0] += w4.x*f; acc[1] += w4.y*f; acc[2] += w4.z*f; acc[3] += w4.w*f;
  }
  #pragma unroll
  for (int j = 0; j < 4; ++j)
    P.out[(size_t)(t0 + tq*4 + j)*1024 + e] = acc[j];
}

// ---------------- cooperative mega-kernel: 512 blocks x 256 thr, 3 grid syncs
__global__ __launch_bounds__(256, 2) void k_mega(Ptrs P){
  __shared__ __align__(16) char smem[SMEM_BYTES];
  cg::grid_group g = cg::this_grid();
  const int bx = blockIdx.x, tid = threadIdx.x;
  phase_prep(P, bx, tid, gridDim.x);
  g.sync();
  phase_gemms(P, bx, tid);
  g.sync();
  phase_score(P, smem, bx, tid);
  g.sync();
  phase_ctx(P, smem, bx, tid);
}

// ---------------- fallback: same phases as separate dispatches
__global__ __launch_bounds__(256) void k_p0(Ptrs P){
  phase_prep(P, blockIdx.x, threadIdx.x, gridDim.x);
}
__global__ __launch_bounds__(256) void k_p1(Ptrs P){
  phase_gemms(P, blockIdx.x, threadIdx.x);
}
__global__ __launch_bounds__(256) void k_p2(Ptrs P){
  __shared__ __align__(16) char smem[SMEM_BYTES];
  phase_score(P, smem, blockIdx.x, threadIdx.x);
}
__global__ __launch_bounds__(256) void k_p3(Ptrs P){
  __shared__ __align__(16) char smem[SMEM_BYTES];
  phase_ctx(P, smem, blockIdx.x, threadIdx.x);
}

extern "C" void kernel_launch(void* const* d_in, const int* in_sizes, int n_in,
                              void* d_out, int out_size, void* d_ws, size_t ws_size,
                              hipStream_t stream) {
  char* ws = (char*)d_ws;
  Ptrs P;
  P.question = (const int*)d_in[0];
  P.img_feat = (const float*)d_in[1];
  P.emb      = (const float*)d_in[2];
  P.W_img    = (const float*)d_in[3];
  P.b_img    = (const float*)d_in[4];
  P.W_ai     = (const float*)d_in[5];
  P.W_aw     = (const float*)d_in[6];
  P.b_aw     = (const float*)d_in[7];
  P.w_att    = (const float*)d_in[8];
  // d_in[9] = b_att: constant pre-softmax shift -> cancels in softmax.
  P.out   = (float*)d_out;
  P.Wb    = (s16*)(ws);                  // 3x512x512 bf16 = 1572864 B
  P.Xb    = (s16*)(ws + 1572864);        // 256x512 bf16   = 262144 B
  P.Eb    = (s16*)(ws + 1835008);        // 1024x512 bf16  = 1048576 B
  P.img   = (float*)(ws + 2883584);      // 256x512 f32    = 524288 B
  P.img_b = (s16*)(ws + 3407872);        // 256x512 bf16   = 262144 B
  P.AWT4  = (float*)(ws + 3670016);      // 128x1024x4 f32 = 2097152 B
  P.ST    = (float*)(ws + 5767168);      // 196x1024 f32   = 802816 B

  void* args[] = { (void*)&P };
  hipError_t e = hipLaunchCooperativeKernel((const void*)k_mega, dim3(512), dim3(256),
                                            args, 0, stream);
  if (e != hipSuccess){
    // cooperative launch unavailable (e.g. under capture) -> 4-dispatch fallback
    hipLaunchKernelGGL(k_p0, dim3(512), dim3(256), 0, stream, P);
    hipLaunchKernelGGL(k_p1, dim3(160), dim3(256), 0, stream, P);
    hipLaunchKernelGGL(k_p2, dim3(400), dim3(256), 0, stream, P);
    hipLaunchKernelGGL(k_p3, dim3(512), dim3(256), 0, stream, P);
  }
}

// Round 9
// 82.310 us; speedup vs baseline: 3.2051x; 3.2051x over previous
//
#include <hip/hip_runtime.h>

#define PRESCALE 2.8853900817779268f   // 2*log2(e): exp2(PRESCALE*x) = e^{2x}

typedef short s16;
typedef unsigned short u16;
typedef unsigned int u32;
typedef __attribute__((ext_vector_type(8))) short short8v;  // 8 bf16 (4 VGPRs)
typedef __attribute__((ext_vector_type(4))) float f4;

// Guaranteed-raw transcendentals: builtin if present, else inline asm.
// (gfx950: VALU->VALU dependencies HW-interlocked; no trans-use hazard.)
#if __has_builtin(__builtin_amdgcn_exp2f)
#define EXP2(x) __builtin_amdgcn_exp2f(x)
#else
static __device__ inline float exp2_raw(float x){ float r; asm("v_exp_f32 %0, %1":"=v"(r):"v"(x)); return r; }
#define EXP2(x) exp2_raw(x)
#endif
#if __has_builtin(__builtin_amdgcn_rcpf)
#define RCP(x) __builtin_amdgcn_rcpf(x)
#else
static __device__ inline float rcp_raw(float x){ float r; asm("v_rcp_f32 %0, %1":"=v"(r):"v"(x)); return r; }
#define RCP(x) rcp_raw(x)
#endif

__device__ inline u16 f2bf(float f){
  union{u32 i; float f;} v; v.f = f;
  u32 r = v.i + 0x7fffu + ((v.i >> 16) & 1u);
  return (u16)(r >> 16);
}

// ---------------- K0: conversions + emb gather. 512 blocks, grid-stride.
__global__ __launch_bounds__(256) void k_prep(
    const float* __restrict__ W_img, const float* __restrict__ W_ai,
    const float* __restrict__ W_aw,  const float* __restrict__ img_feat,
    const int* __restrict__ question, const float* __restrict__ emb,
    s16* __restrict__ Wb, s16* __restrict__ Xb, s16* __restrict__ Eb,
    float* __restrict__ out){
  for (int g = blockIdx.x*256 + threadIdx.x; g < 360448; g += gridDim.x*256){
    if (g < 196608){                    // 3 weights -> bf16 (PRESCALE on W_ai, W_aw)
      const int i = g*4, w = i >> 18;
      const float sc = (w == 0) ? 1.f : PRESCALE;
      const float* src = (w==0) ? W_img : ((w==1) ? W_ai : W_aw);
      float4 v = *reinterpret_cast<const float4*>(src + (i & 262143));
      ushort4 o; o.x=f2bf(v.x*sc); o.y=f2bf(v.y*sc); o.z=f2bf(v.z*sc); o.w=f2bf(v.w*sc);
      *reinterpret_cast<ushort4*>(Wb + i) = o;
    } else if (g < 229376){             // Xb 256x512 bf16, zero-pad rows >=196
      const int i = (g - 196608)*4;
      ushort4 o = make_ushort4(0,0,0,0);
      if ((i >> 9) < 196){
        float4 v = *reinterpret_cast<const float4*>(img_feat + i);
        o.x=f2bf(v.x); o.y=f2bf(v.y); o.z=f2bf(v.z); o.w=f2bf(v.w);
      }
      *reinterpret_cast<ushort4*>(Xb + i) = o;
    } else {                            // Eb 1024x512 bf16 + f32 copy to out[:,512:]
      const int i = (g - 229376)*4;
      const int t = i >> 9, c = i & 511;
      float4 v = *reinterpret_cast<const float4*>(emb + (size_t)question[t]*512 + c);
      *reinterpret_cast<float4*>(out + (size_t)t*1024 + 512 + c) = v;
      ushort4 o; o.x=f2bf(v.x); o.y=f2bf(v.y); o.z=f2bf(v.z); o.w=f2bf(v.w);
      *reinterpret_cast<ushort4*>(Eb + i) = o;
    }
  }
}

// 64x64 MFMA tile core: D[i][j] = sum_k A[i][k]*B[j][k], K=512 bf16.
__device__ inline void mfma_core(const s16* __restrict__ A, const s16* __restrict__ B,
                                 int m0, int n0, int lr, int lg, f4 acc[2][2]){
  const s16* pa0 = A + (size_t)(m0 + lr)*512 + lg*8;
  const s16* pa1 = pa0 + 16*512;
  const s16* pb0 = B + (size_t)(n0 + lr)*512 + lg*8;
  const s16* pb1 = pb0 + 16*512;
  #pragma unroll 4
  for (int k = 0; k < 512; k += 32){
    short8v a0 = *reinterpret_cast<const short8v*>(pa0 + k);
    short8v a1 = *reinterpret_cast<const short8v*>(pa1 + k);
    short8v b0 = *reinterpret_cast<const short8v*>(pb0 + k);
    short8v b1 = *reinterpret_cast<const short8v*>(pb1 + k);
    acc[0][0] = __builtin_amdgcn_mfma_f32_16x16x32_bf16(a0, b0, acc[0][0], 0, 0, 0);
    acc[0][1] = __builtin_amdgcn_mfma_f32_16x16x32_bf16(a0, b1, acc[0][1], 0, 0, 0);
    acc[1][0] = __builtin_amdgcn_mfma_f32_16x16x32_bf16(a1, b0, acc[1][0], 0, 0, 0);
    acc[1][1] = __builtin_amdgcn_mfma_f32_16x16x32_bf16(a1, b1, acc[1][1], 0, 0, 0);
  }
}

// ---------------- K1: img GEMM (blocks 0..31) + AWT GEMM (blocks 32..159).
__global__ __launch_bounds__(256) void k_gemms(
    const s16* __restrict__ Xb, const s16* __restrict__ Wb_img,
    const s16* __restrict__ Wb_aw, const s16* __restrict__ Eb,
    const float* __restrict__ b_img, const float* __restrict__ b_aw,
    float* __restrict__ img, s16* __restrict__ img_b,
    float* __restrict__ AWT4){
  const int tid = threadIdx.x, w = tid>>6, l = tid&63;
  const int lr = l & 15, lg = l >> 4;
  f4 acc[2][2] = {};
  if (blockIdx.x < 32){
    const int m0 = (blockIdx.x >> 3)*64 + (w>>1)*32;
    const int n0 = (blockIdx.x & 7)*64 + (w&1)*32;
    mfma_core(Xb, Wb_img, m0, n0, lr, lg, acc);
    #pragma unroll
    for (int i = 0; i < 2; ++i){
      #pragma unroll
      for (int j = 0; j < 2; ++j){
        const int nn = n0 + j*16 + lr;
        const float bc = b_img[nn];
        #pragma unroll
        for (int p = 0; p < 4; ++p){
          const int mm = m0 + i*16 + lg*4 + p;
          float v = fmaxf(acc[i][j][p] + bc, 0.f);
          img[(size_t)mm*512 + nn] = v;
          img_b[(size_t)mm*512 + nn] = (s16)f2bf(v);
        }
      }
    }
  } else {
    const int blk = blockIdx.x - 32;
    const int m0 = (blk >> 4)*64 + (w>>1)*32;     // h
    const int n0 = (blk & 15)*64 + (w&1)*32;      // t
    mfma_core(Wb_aw, Eb, m0, n0, lr, lg, acc);
    #pragma unroll
    for (int i = 0; i < 2; ++i){
      const int mb = m0 + i*16 + lg*4;            // h = mb+p, mb%4==0
      #pragma unroll
      for (int j = 0; j < 2; ++j){
        const int nn = n0 + j*16 + lr;
        f4 o;
        #pragma unroll
        for (int p = 0; p < 4; ++p)
          o[p] = acc[i][j][p] + b_aw[mb+p]*PRESCALE;
        *reinterpret_cast<f4*>(AWT4 + (size_t)(mb>>2)*4096 + nn*4) = o;
      }
    }
  }
}

// ---------------- K2: AI = img_b @ Wb_aiT (PRESCALE folded in Wb_ai). 32 blocks.
__global__ __launch_bounds__(256) void k_ai(
    const s16* __restrict__ img_b, const s16* __restrict__ Wb_ai,
    float* __restrict__ AI){
  const int tid = threadIdx.x, w = tid>>6, l = tid&63;
  const int lr = l & 15, lg = l >> 4;
  const int m0 = (blockIdx.x >> 3)*64 + (w>>1)*32;
  const int n0 = (blockIdx.x & 7)*64 + (w&1)*32;
  f4 acc[2][2] = {};
  mfma_core(img_b, Wb_ai, m0, n0, lr, lg, acc);
  #pragma unroll
  for (int i = 0; i < 2; ++i)
    #pragma unroll
    for (int j = 0; j < 2; ++j){
      const int nn = n0 + j*16 + lr;
      #pragma unroll
      for (int p = 0; p < 4; ++p){
        const int mm = m0 + i*16 + lg*4 + p;
        AI[(size_t)mm*512 + nn] = acc[i][j][p];
      }
    }
}

// ---------------- K3: score. 256 blocks x 512 thr (1/CU, 4 waves/SIMD in loop).
// Block = 16 r x 64 t; wave w owns rows 2w, 2w+1; lane <-> t.
// ST[r][t] = sum_h w[h]*rcp(exp2(AI'[r][h]+AW'[h][t])+1); softmax==softmax(-2*ST).
__global__ __launch_bounds__(512) void k_score(
    const float* __restrict__ AI, const float* __restrict__ AWT4,
    const float* __restrict__ w_att, float* __restrict__ ST){
  __shared__ float ais[16*512 + 512];
  float* wsh = ais + 16*512;
  const int tid = threadIdx.x, w = tid>>6, l = tid&63;
  const int rq = blockIdx.x >> 4, tq = blockIdx.x & 15;   // rq 0..15, tq 0..15
  {
    const f4* src = reinterpret_cast<const f4*>(AI + (size_t)rq*16*512);
    f4* dst = reinterpret_cast<f4*>(ais);
    #pragma unroll
    for (int i = 0; i < 4; ++i) dst[tid + i*512] = src[tid + i*512];
    if (tid < 128)
      reinterpret_cast<f4*>(wsh)[tid] = reinterpret_cast<const f4*>(w_att)[tid];
  }
  __syncthreads();
  const float* a0 = ais + (size_t)(w*2)*512;
  const float* a1 = a0 + 512;
  const int t = tq*64 + l;
  const float* ap = AWT4 + (size_t)t*4;
  float s0=0.f, s1=0.f, s2=0.f, s3=0.f;
  #pragma unroll 8
  for (int hg = 0; hg < 128; ++hg){
    f4 x  = *reinterpret_cast<const f4*>(ap + (size_t)hg*4096);
    f4 av = *reinterpret_cast<const f4*>(a0 + hg*4);
    f4 bv = *reinterpret_cast<const f4*>(a1 + hg*4);
    f4 wv = *reinterpret_cast<const f4*>(wsh + hg*4);
    s0 += wv.x*RCP(EXP2(av.x+x.x)+1.f) + wv.y*RCP(EXP2(av.y+x.y)+1.f);
    s1 += wv.z*RCP(EXP2(av.z+x.z)+1.f) + wv.w*RCP(EXP2(av.w+x.w)+1.f);
    s2 += wv.x*RCP(EXP2(bv.x+x.x)+1.f) + wv.y*RCP(EXP2(bv.y+x.y)+1.f);
    s3 += wv.z*RCP(EXP2(bv.z+x.z)+1.f) + wv.w*RCP(EXP2(bv.w+x.w)+1.f);
  }
  const int r = rq*16 + w*2;   // rows 0..255; rows >=196 garbage, never read
  ST[(size_t)r*1024 + t]     = s0+s1;
  ST[(size_t)(r+1)*1024 + t] = s2+s3;
}

// ---------------- K4: softmax(-2*ST) (fold /196) + ctx = w @ img.
// grid(64,8): 16 tokens x 64 e per block, 256 thr.
__global__ __launch_bounds__(256) void k_ctx(
    const float* __restrict__ ST, const float* __restrict__ img,
    float* __restrict__ out){
  __shared__ float wgt[196][16];
  __shared__ float red[16][16];
  const int tid = threadIdx.x;
  const int t0 = blockIdx.x*16, e0 = blockIdx.y*64;
  const int rs = tid>>4, tl = tid&15;

  float m = 1e30f;
  for (int k = 0; k < 13; ++k){
    const int r = rs + 16*k;
    if (r < 196) m = fminf(m, ST[(size_t)r*1024 + t0 + tl]);
  }
  red[rs][tl] = m;
  __syncthreads();
  if (tid < 16){
    float mm = red[0][tid];
    #pragma unroll
    for (int i = 1; i < 16; ++i) mm = fminf(mm, red[i][tid]);
    red[0][tid] = mm;
  }
  __syncthreads();
  const float mt = red[0][tl];
  float sum = 0.f;
  for (int k = 0; k < 13; ++k){
    const int r = rs + 16*k;
    if (r < 196){
      float p = EXP2(PRESCALE*(mt - ST[(size_t)r*1024 + t0 + tl]));
      wgt[r][tl] = p;
      sum += p;
    }
  }
  __syncthreads();
  red[rs][tl] = sum;
  __syncthreads();
  if (tid < 16){
    float ss = 0.f;
    #pragma unroll
    for (int i = 0; i < 16; ++i) ss += red[i][tid];
    red[0][tid] = 1.f / (ss * 196.f);
  }
  __syncthreads();
  const float inv = red[0][tl];
  for (int k = 0; k < 13; ++k){
    const int r = rs + 16*k;
    if (r < 196) wgt[r][tl] *= inv;
  }
  __syncthreads();

  const int e = e0 + (tid & 63), tq = tid >> 6;
  float acc[4] = {0.f, 0.f, 0.f, 0.f};
  const float* ip = img + e;
  #pragma unroll 4
  for (int r = 0; r < 196; ++r){
    const float f = ip[(size_t)r*512];
    float4 w4 = *reinterpret_cast<const float4*>(&wgt[r][tq*4]);
    acc[0] += w4.x*f; acc[1] += w4.y*f; acc[2] += w4.z*f; acc[3] += w4.w*f;
  }
  #pragma unroll
  for (int j = 0; j < 4; ++j)
    out[(size_t)(t0 + tq*4 + j)*1024 + e] = acc[j];
}

extern "C" void kernel_launch(void* const* d_in, const int* in_sizes, int n_in,
                              void* d_out, int out_size, void* d_ws, size_t ws_size,
                              hipStream_t stream) {
  const int*   question = (const int*)d_in[0];
  const float* img_feat = (const float*)d_in[1];
  const float* emb      = (const float*)d_in[2];
  const float* W_img    = (const float*)d_in[3];
  const float* b_img    = (const float*)d_in[4];
  const float* W_ai     = (const float*)d_in[5];
  const float* W_aw     = (const float*)d_in[6];
  const float* b_aw     = (const float*)d_in[7];
  const float* w_att    = (const float*)d_in[8];
  // d_in[9] = b_att: constant pre-softmax shift -> cancels in softmax.
  float* out = (float*)d_out;

  char* ws = (char*)d_ws;
  s16*   Wb    = (s16*)(ws);                  // 3x512x512 bf16 = 1572864 B
  s16*   Xb    = (s16*)(ws + 1572864);        // 256x512 bf16   = 262144 B
  s16*   Eb    = (s16*)(ws + 1835008);        // 1024x512 bf16  = 1048576 B
  float* img   = (float*)(ws + 2883584);      // 256x512 f32    = 524288 B
  s16*   img_b = (s16*)(ws + 3407872);        // 256x512 bf16   = 262144 B
  float* AI    = (float*)(ws + 3670016);      // 256x512 f32    = 524288 B
  float* AWT4  = (float*)(ws + 4194304);      // 128x1024x4 f32 = 2097152 B
  float* ST    = (float*)(ws + 6291456);      // 256x1024 f32   = 1048576 B

  hipLaunchKernelGGL(k_prep,  dim3(512),   dim3(256), 0, stream,
                     W_img, W_ai, W_aw, img_feat, question, emb, Wb, Xb, Eb, out);
  hipLaunchKernelGGL(k_gemms, dim3(160),   dim3(256), 0, stream,
                     Xb, Wb, Wb + 2*262144, Eb, b_img, b_aw, img, img_b, AWT4);
  hipLaunchKernelGGL(k_ai,    dim3(32),    dim3(256), 0, stream,
                     img_b, Wb + 262144, AI);
  hipLaunchKernelGGL(k_score, dim3(256),   dim3(512), 0, stream,
                     AI, AWT4, w_att, ST);
  hipLaunchKernelGGL(k_ctx,   dim3(64,8),  dim3(256), 0, stream, ST, img, out);
}

// Round 10
// 79.882 us; speedup vs baseline: 3.3025x; 1.0304x over previous
//
#include <hip/hip_runtime.h>

#define PRESCALE 2.8853900817779268f   // 2*log2(e): exp2(PRESESCALE*x) -- e^{2x}

typedef short s16;
typedef unsigned short u16;
typedef unsigned int u32;
typedef __attribute__((ext_vector_type(8))) short short8v;  // 8 bf16 (4 VGPRs)
typedef __attribute__((ext_vector_type(4))) float f4;

// Guaranteed-raw transcendentals: builtin if present, else inline asm.
#if __has_builtin(__builtin_amdgcn_exp2f)
#define EXP2(x) __builtin_amdgcn_exp2f(x)
#else
static __device__ inline float exp2_raw(float x){ float r; asm("v_exp_f32 %0, %1":"=v"(r):"v"(x)); return r; }
#define EXP2(x) exp2_raw(x)
#endif
#if __has_builtin(__builtin_amdgcn_rcpf)
#define RCP(x) __builtin_amdgcn_rcpf(x)
#else
static __device__ inline float rcp_raw(float x){ float r; asm("v_rcp_f32 %0, %1":"=v"(r):"v"(x)); return r; }
#define RCP(x) rcp_raw(x)
#endif

__device__ inline u16 f2bf(float f){
  union{u32 i; float f;} v; v.f = f;
  u32 r = v.i + 0x7fffu + ((v.i >> 16) & 1u);
  return (u16)(r >> 16);
}

// ---------------- K0: conversions + emb gather. 512 blocks, grid-stride.
__global__ __launch_bounds__(256) void k_prep(
    const float* __restrict__ W_img, const float* __restrict__ W_ai,
    const float* __restrict__ W_aw,  const float* __restrict__ img_feat,
    const int* __restrict__ question, const float* __restrict__ emb,
    s16* __restrict__ Wb, s16* __restrict__ Xb, s16* __restrict__ Eb,
    float* __restrict__ out){
  for (int g = blockIdx.x*256 + threadIdx.x; g < 360448; g += gridDim.x*256){
    if (g < 196608){                    // 3 weights -> bf16 (PRESCALE on W_ai, W_aw)
      const int i = g*4, w = i >> 18;
      const float sc = (w == 0) ? 1.f : PRESCALE;
      const float* src = (w==0) ? W_img : ((w==1) ? W_ai : W_aw);
      float4 v = *reinterpret_cast<const float4*>(src + (i & 262143));
      ushort4 o; o.x=f2bf(v.x*sc); o.y=f2bf(v.y*sc); o.z=f2bf(v.z*sc); o.w=f2bf(v.w*sc);
      *reinterpret_cast<ushort4*>(Wb + i) = o;
    } else if (g < 229376){             // Xb 256x512 bf16, zero-pad rows >=196
      const int i = (g - 196608)*4;
      ushort4 o = make_ushort4(0,0,0,0);
      if ((i >> 9) < 196){
        float4 v = *reinterpret_cast<const float4*>(img_feat + i);
        o.x=f2bf(v.x); o.y=f2bf(v.y); o.z=f2bf(v.z); o.w=f2bf(v.w);
      }
      *reinterpret_cast<ushort4*>(Xb + i) = o;
    } else {                            // Eb 1024x512 bf16 + f32 copy to out[:,512:]
      const int i = (g - 229376)*4;
      const int t = i >> 9, c = i & 511;
      float4 v = *reinterpret_cast<const float4*>(emb + (size_t)question[t]*512 + c);
      *reinterpret_cast<float4*>(out + (size_t)t*1024 + 512 + c) = v;
      ushort4 o; o.x=f2bf(v.x); o.y=f2bf(v.y); o.z=f2bf(v.z); o.w=f2bf(v.w);
      *reinterpret_cast<ushort4*>(Eb + i) = o;
    }
  }
}

// 64x64 MFMA tile core: D[i][j] = sum_k A[i][k]*B[j][k], K=512 bf16.
__device__ inline void mfma_core(const s16* __restrict__ A, const s16* __restrict__ B,
                                 int m0, int n0, int lr, int lg, f4 acc[2][2]){
  const s16* pa0 = A + (size_t)(m0 + lr)*512 + lg*8;
  const s16* pa1 = pa0 + 16*512;
  const s16* pb0 = B + (size_t)(n0 + lr)*512 + lg*8;
  const s16* pb1 = pb0 + 16*512;
  #pragma unroll 4
  for (int k = 0; k < 512; k += 32){
    short8v a0 = *reinterpret_cast<const short8v*>(pa0 + k);
    short8v a1 = *reinterpret_cast<const short8v*>(pa1 + k);
    short8v b0 = *reinterpret_cast<const short8v*>(pb0 + k);
    short8v b1 = *reinterpret_cast<const short8v*>(pb1 + k);
    acc[0][0] = __builtin_amdgcn_mfma_f32_16x16x32_bf16(a0, b0, acc[0][0], 0, 0, 0);
    acc[0][1] = __builtin_amdgcn_mfma_f32_16x16x32_bf16(a0, b1, acc[0][1], 0, 0, 0);
    acc[1][0] = __builtin_amdgcn_mfma_f32_16x16x32_bf16(a1, b0, acc[1][0], 0, 0, 0);
    acc[1][1] = __builtin_amdgcn_mfma_f32_16x16x32_bf16(a1, b1, acc[1][1], 0, 0, 0);
  }
}

// ---------------- K1: img GEMM (blocks 0..31) + AWT GEMM (blocks 32..159).
__global__ __launch_bounds__(256) void k_gemms(
    const s16* __restrict__ Xb, const s16* __restrict__ Wb_img,
    const s16* __restrict__ Wb_aw, const s16* __restrict__ Eb,
    const float* __restrict__ b_img, const float* __restrict__ b_aw,
    float* __restrict__ img, s16* __restrict__ img_b,
    float* __restrict__ AWT4){
  const int tid = threadIdx.x, w = tid>>6, l = tid&63;
  const int lr = l & 15, lg = l >> 4;
  f4 acc[2][2] = {};
  if (blockIdx.x < 32){
    const int m0 = (blockIdx.x >> 3)*64 + (w>>1)*32;
    const int n0 = (blockIdx.x & 7)*64 + (w&1)*32;
    mfma_core(Xb, Wb_img, m0, n0, lr, lg, acc);
    #pragma unroll
    for (int i = 0; i < 2; ++i){
      #pragma unroll
      for (int j = 0; j < 2; ++j){
        const int nn = n0 + j*16 + lr;
        const float bc = b_img[nn];
        #pragma unroll
        for (int p = 0; p < 4; ++p){
          const int mm = m0 + i*16 + lg*4 + p;
          float v = fmaxf(acc[i][j][p] + bc, 0.f);
          img[(size_t)mm*512 + nn] = v;
          img_b[(size_t)mm*512 + nn] = (s16)f2bf(v);
        }
      }
    }
  } else {
    const int blk = blockIdx.x - 32;
    const int m0 = (blk >> 4)*64 + (w>>1)*32;     // h
    const int n0 = (blk & 15)*64 + (w&1)*32;      // t
    mfma_core(Wb_aw, Eb, m0, n0, lr, lg, acc);
    #pragma unroll
    for (int i = 0; i < 2; ++i){
      const int mb = m0 + i*16 + lg*4;            // h = mb+p, mb%4==0
      #pragma unroll
      for (int j = 0; j < 2; ++j){
        const int nn = n0 + j*16 + lr;
        f4 o;
        #pragma unroll
        for (int p = 0; p < 4; ++p)
          o[p] = acc[i][j][p] + b_aw[mb+p]*PRESCALE;
        *reinterpret_cast<f4*>(AWT4 + (size_t)(mb>>2)*4096 + nn*4) = o;
      }
    }
  }
}

// ---------------- K2: AI = img_b @ Wb_aiT (PRESCALE folded in Wb_ai). 32 blocks.
__global__ __launch_bounds__(256) void k_ai(
    const s16* __restrict__ img_b, const s16* __restrict__ Wb_ai,
    float* __restrict__ AI){
  const int tid = threadIdx.x, w = tid>>6, l = tid&63;
  const int lr = l & 15, lg = l >> 4;
  const int m0 = (blockIdx.x >> 3)*64 + (w>>1)*32;
  const int n0 = (blockIdx.x & 7)*64 + (w&1)*32;
  f4 acc[2][2] = {};
  mfma_core(img_b, Wb_ai, m0, n0, lr, lg, acc);
  #pragma unroll
  for (int i = 0; i < 2; ++i)
    #pragma unroll
    for (int j = 0; j < 2; ++j){
      const int nn = n0 + j*16 + lr;
      #pragma unroll
      for (int p = 0; p < 4; ++p){
        const int mm = m0 + i*16 + lg*4 + p;
        AI[(size_t)mm*512 + nn] = acc[i][j][p];
      }
    }
}

// ---------------- K3: score, h-chunked with aw in registers. grid(40,8,2) x 512.
// Block: 5 r x 64 h-chunk x 512 t (8 waves <-> 8 t-tiles of 64).
// STp[hc][r][t] = sum_{h in chunk hc} w[h]*rcp(exp2(AI'[r][h]+AW'[h][t])+1)
// (k_ctx sums the 8 chunk partials; softmax(score) == softmax(-2*ST)).
#define RB5 5
__global__ __launch_bounds__(512) void k_score(
    const float* __restrict__ AI, const float* __restrict__ AWT4,
    const float* __restrict__ w_att, float* __restrict__ STp){
  __shared__ float ais[RB5][64];
  __shared__ float wsh[64];
  const int tid = threadIdx.x, w = tid>>6, l = tid&63;
  const int rr = blockIdx.x, hc = blockIdx.y, th = blockIdx.z;
  const int r0 = rr*RB5, h0 = hc*64;
  if (tid < 80){                      // stage 5x64 AI tile (row-clamped)
    const int i = tid >> 4, j = tid & 15;
    const int r = min(r0 + i, 195);
    *reinterpret_cast<f4*>(&ais[i][j*4]) =
        *reinterpret_cast<const f4*>(AI + (size_t)r*512 + h0 + j*4);
  } else if (tid < 96){               // stage w_att chunk
    const int j = tid - 80;
    *reinterpret_cast<f4*>(&wsh[j*4]) =
        *reinterpret_cast<const f4*>(w_att + h0 + j*4);
  }
  const int t = th*512 + w*64 + l;
  const int hg0 = hc*16;
  f4 awr[16];                         // aw[h][t] for the 64-h chunk, per-lane
  #pragma unroll
  for (int j = 0; j < 16; ++j)
    awr[j] = *reinterpret_cast<const f4*>(AWT4 + (size_t)(hg0+j)*4096 + t*4);
  __syncthreads();
  #pragma unroll
  for (int i = 0; i < RB5; ++i){
    const int r = r0 + i;
    if (r >= 196) break;
    float a0=0.f, a1=0.f, a2=0.f, a3=0.f;
    #pragma unroll
    for (int j = 0; j < 16; ++j){
      f4 av = *reinterpret_cast<const f4*>(&ais[i][j*4]);
      f4 wv = *reinterpret_cast<const f4*>(&wsh[j*4]);
      a0 += wv.x*RCP(EXP2(av.x+awr[j].x)+1.f);
      a1 += wv.y*RCP(EXP2(av.y+awr[j].y)+1.f);
      a2 += wv.z*RCP(EXP2(av.z+awr[j].z)+1.f);
      a3 += wv.w*RCP(EXP2(av.w+awr[j].w)+1.f);
    }
    STp[((size_t)hc<<18) + (size_t)r*1024 + t] = (a0+a1)+(a2+a3);
  }
}

// ---------------- K4: sum partials + softmax(-2*ST) (fold /196) + ctx = w @ img.
// grid(64,8): 16 tokens x 64 e per block, 256 thr.
__global__ __launch_bounds__(256) void k_ctx(
    const float* __restrict__ STp, const float* __restrict__ img,
    float* __restrict__ out){
  __shared__ float wgt[196][16];
  __shared__ float red[16][16];
  const int tid = threadIdx.x;
  const int t0 = blockIdx.x*16, e0 = blockIdx.y*64;
  const int rs = tid>>4, tl = tid&15;

  // fused: sum 8 h-chunk partials into wgt + per-thread min
  float m = 1e30f;
  for (int k = 0; k < 13; ++k){
    const int r = rs + 16*k;
    if (r < 196){
      float s = 0.f;
      #pragma unroll
      for (int c = 0; c < 8; ++c)
        s += STp[((size_t)c<<18) + (size_t)r*1024 + t0 + tl];
      wgt[r][tl] = s;
      m = fminf(m, s);
    }
  }
  red[rs][tl] = m;
  __syncthreads();
  if (tid < 16){
    float mm = red[0][tid];
    #pragma unroll
    for (int i = 1; i < 16; ++i) mm = fminf(mm, red[i][tid]);
    red[0][tid] = mm;
  }
  __syncthreads();
  const float mt = red[0][tl];
  float sum = 0.f;
  for (int k = 0; k < 13; ++k){
    const int r = rs + 16*k;
    if (r < 196){
      float p = EXP2(PRESCALE*(mt - wgt[r][tl]));
      wgt[r][tl] = p;
      sum += p;
    }
  }
  __syncthreads();
  red[rs][tl] = sum;
  __syncthreads();
  if (tid < 16){
    float ss = 0.f;
    #pragma unroll
    for (int i = 0; i < 16; ++i) ss += red[i][tid];
    red[0][tid] = 1.f / (ss * 196.f);
  }
  __syncthreads();
  const float inv = red[0][tl];
  for (int k = 0; k < 13; ++k){
    const int r = rs + 16*k;
    if (r < 196) wgt[r][tl] *= inv;
  }
  __syncthreads();

  const int e = e0 + (tid & 63), tq = tid >> 6;
  float acc[4] = {0.f, 0.f, 0.f, 0.f};
  const float* ip = img + e;
  #pragma unroll 4
  for (int r = 0; r < 196; ++r){
    const float f = ip[(size_t)r*512];
    float4 w4 = *reinterpret_cast<const float4*>(&wgt[r][tq*4]);
    acc[0] += w4.x*f; acc[1] += w4.y*f; acc[2] += w4.z*f; acc[3] += w4.w*f;
  }
  #pragma unroll
  for (int j = 0; j < 4; ++j)
    out[(size_t)(t0 + tq*4 + j)*1024 + e] = acc[j];
}

extern "C" void kernel_launch(void* const* d_in, const int* in_sizes, int n_in,
                              void* d_out, int out_size, void* d_ws, size_t ws_size,
                              hipStream_t stream) {
  const int*   question = (const int*)d_in[0];
  const float* img_feat = (const float*)d_in[1];
  const float* emb      = (const float*)d_in[2];
  const float* W_img    = (const float*)d_in[3];
  const float* b_img    = (const float*)d_in[4];
  const float* W_ai     = (const float*)d_in[5];
  const float* W_aw     = (const float*)d_in[6];
  const float* b_aw     = (const float*)d_in[7];
  const float* w_att    = (const float*)d_in[8];
  // d_in[9] = b_att: constant pre-softmax shift -> cancels in softmax.
  float* out = (float*)d_out;

  char* ws = (char*)d_ws;
  s16*   Wb    = (s16*)(ws);                  // 3x512x512 bf16 = 1572864 B
  s16*   Xb    = (s16*)(ws + 1572864);        // 256x512 bf16   = 262144 B
  s16*   Eb    = (s16*)(ws + 1835008);        // 1024x512 bf16  = 1048576 B
  float* img   = (float*)(ws + 2883584);      // 256x512 f32    = 524288 B
  s16*   img_b = (s16*)(ws + 3407872);        // 256x512 bf16   = 262144 B
  float* AI    = (float*)(ws + 3670016);      // 256x512 f32    = 524288 B
  float* AWT4  = (float*)(ws + 4194304);      // 128x1024x4 f32 = 2097152 B
  float* STp   = (float*)(ws + 6291456);      // 8x256x1024 f32 = 8388608 B

  hipLaunchKernelGGL(k_prep,  dim3(512),    dim3(256), 0, stream,
                     W_img, W_ai, W_aw, img_feat, question, emb, Wb, Xb, Eb, out);
  hipLaunchKernelGGL(k_gemms, dim3(160),    dim3(256), 0, stream,
                     Xb, Wb, Wb + 2*262144, Eb, b_img, b_aw, img, img_b, AWT4);
  hipLaunchKernelGGL(k_ai,    dim3(32),     dim3(256), 0, stream,
                     img_b, Wb + 262144, AI);
  hipLaunchKernelGGL(k_score, dim3(40,8,2), dim3(512), 0, stream,
                     AI, AWT4, w_att, STp);
  hipLaunchKernelGGL(k_ctx,   dim3(64,8),   dim3(256), 0, stream, STp, img, out);
}